// Round 4
// baseline (375.061 us; speedup 1.0000x reference)
//
#include <hip/hip_runtime.h>
#include <cstdint>
#include <cstddef>

// N=100000, E=300000, B=50000, L=4, D_EMB=128, D_HID=64, H=8. fp32 in/out.
// R4: fused pipeline. Y = feat @ [Wi;Wp].T (split-bf16 MFMA, P-projection fused
// via LDS). CSR of kept edges stores mp rows directly (int4). Single k_agg does
// online softmax + aggregation per flagged node (no logits/mpc buffers).

typedef __attribute__((ext_vector_type(8))) short bf16x8;
typedef __attribute__((ext_vector_type(4))) float f32x4;

__device__ __forceinline__ unsigned short f2bf(float f) {
    unsigned u = __float_as_uint(f);
    unsigned r = u + 0x7fffu + ((u >> 16) & 1u);
    return (unsigned short)(r >> 16);
}
__device__ __forceinline__ float bf2f(unsigned short h) {
    return __uint_as_float((unsigned)h << 16);
}

// ---------------------------------------------------------------------------
// blocks [0,64): pack [Wi;Wp].T into MFMA B-frag order, split hi/lo bf16.
// blocks [64,..): mult[n]++ over batch_nodes; first toucher appends to flagged.
__global__ __launch_bounds__(256) void k_prep(
    const float* __restrict__ Wi, const float* __restrict__ Wp,
    unsigned short* __restrict__ Whi, unsigned short* __restrict__ Wlo,
    const int* __restrict__ batch_nodes, int* __restrict__ mult,
    int* __restrict__ flagged, int* __restrict__ nf, int B) {
    if (blockIdx.x < 64) {
        int t = blockIdx.x * 256 + threadIdx.x;
        int j = t & 7, L = (t >> 3) & 63, c = (t >> 9) & 7, s = t >> 12;
        int k = s * 32 + (L >> 4) * 8 + j;
        int n = c * 16 + (L & 15);
        float v = (n < 64) ? Wi[n * 128 + k] : Wp[(n - 64) * 128 + k];
        unsigned short h = f2bf(v);
        Whi[t] = h;
        Wlo[t] = f2bf(v - bf2f(h));
    } else {
        int i = (int)(blockIdx.x - 64) * 256 + threadIdx.x;
        if (i < B) {
            int n = batch_nodes[i];
            if (atomicAdd(&mult[n], 1) == 0) {
                int p = atomicAdd(nf, 1);
                flagged[p] = n;
            }
        }
    }
}

// ---------------------------------------------------------------------------
// Dense GEMM Ybf[M x 128] = feat @ B (split-bf16, 3 MFMA) + fused P projection:
// P[n,i] = Yi[n].attn_i, P[n,8+i] = Yp[n].attn_i  (computed from fp32 acc).
__global__ __launch_bounds__(256) void k_dense(
    const float* __restrict__ feat, const unsigned short* __restrict__ Whi,
    const unsigned short* __restrict__ Wlo, const float* __restrict__ attn,
    unsigned short* __restrict__ Ybf, float* __restrict__ P, int M) {
    __shared__ float sY[64 * 132];   // [lrow][col], stride 132 (16B-aligned rows)
    __shared__ float sAt[512];       // attn [8][64]
    int t = threadIdx.x;
    sAt[t] = attn[t];
    sAt[256 + t] = attn[256 + t];

    int wave = t >> 6;
    int L = t & 63;
    int m = L & 15, q = L >> 4;
    int R0 = blockIdx.x * 64 + wave * 16;

    f32x4 acc[8];
#pragma unroll
    for (int c = 0; c < 8; ++c) acc[c] = (f32x4){0.f, 0.f, 0.f, 0.f};

    int rowc = R0 + m; if (rowc > M - 1) rowc = M - 1;
    const float* arow = feat + (size_t)rowc * 128;

    for (int s = 0; s < 4; ++s) {
        const float4* ap = (const float4*)(arow + s * 32 + q * 8);
        float4 a0 = ap[0], a1 = ap[1];
        float av[8] = {a0.x, a0.y, a0.z, a0.w, a1.x, a1.y, a1.z, a1.w};
        bf16x8 ahi, alo;
#pragma unroll
        for (int j = 0; j < 8; ++j) {
            unsigned short h = f2bf(av[j]);
            ahi[j] = (short)h;
            alo[j] = (short)f2bf(av[j] - bf2f(h));
        }
#pragma unroll
        for (int c = 0; c < 8; ++c) {
            const bf16x8 bh = *(const bf16x8*)(Whi + ((s * 8 + c) * 512 + L * 8));
            const bf16x8 bl = *(const bf16x8*)(Wlo + ((s * 8 + c) * 512 + L * 8));
            acc[c] = __builtin_amdgcn_mfma_f32_16x16x32_bf16(ahi, bh, acc[c], 0, 0, 0);
            acc[c] = __builtin_amdgcn_mfma_f32_16x16x32_bf16(ahi, bl, acc[c], 0, 0, 0);
            acc[c] = __builtin_amdgcn_mfma_f32_16x16x32_bf16(alo, bh, acc[c], 0, 0, 0);
        }
    }
    // C/D layout: col = lane&15, row = (lane>>4)*4 + reg
#pragma unroll
    for (int c = 0; c < 8; ++c) {
#pragma unroll
        for (int r = 0; r < 4; ++r) {
            int lrow = wave * 16 + q * 4 + r;
            int row = R0 + q * 4 + r;
            sY[lrow * 132 + c * 16 + m] = acc[c][r];
            if (row < M) Ybf[(size_t)row * 128 + c * 16 + m] = f2bf(acc[c][r]);
        }
    }
    __syncthreads();

    // P phase: 128 threads, thread = (row 0..63, half 0..1)
    if (t < 128) {
        int row = t >> 1, half = t & 1;
        int g = blockIdx.x * 64 + row;
        if (g < M) {
            float p[8];
#pragma unroll
            for (int i = 0; i < 8; ++i) p[i] = 0.f;
            const float* yr = &sY[row * 132 + half * 64];
#pragma unroll 4
            for (int k4 = 0; k4 < 16; ++k4) {
                float4 y = *(const float4*)(yr + k4 * 4);
#pragma unroll
                for (int i = 0; i < 8; ++i) {
                    const float* a = &sAt[i * 64 + k4 * 4];
                    p[i] += y.x * a[0] + y.y * a[1] + y.z * a[2] + y.w * a[3];
                }
            }
#pragma unroll
            for (int i = 0; i < 8; ++i) P[(size_t)g * 16 + half * 8 + i] = p[i];
        }
    }
}

// ---------------------------------------------------------------------------
// count[d]++ for kept edges; append (e,d) to kept list.
__global__ __launch_bounds__(256) void k_hist(
    const int* __restrict__ edge_dst, const int* __restrict__ mult,
    int* __restrict__ count, int2* __restrict__ kept, int* __restrict__ keptCnt,
    int E) {
    int e = blockIdx.x * 256 + threadIdx.x;
    if (e >= E) return;
    int d = edge_dst[e];
    if (mult[d] > 0) {
        atomicAdd(&count[d], 1);
        int p = atomicAdd(keptCnt, 1);
        kept[p] = make_int2(e, d);
    }
}

// exclusive scan of count -> offsets[0..N], cursor copy
__global__ __launch_bounds__(256) void k_scan1(
    const int* __restrict__ count, int* __restrict__ excl, int* __restrict__ partials, int N) {
    __shared__ int lds[256];
    int t = threadIdx.x, i = blockIdx.x * 256 + t;
    int c = (i < N) ? count[i] : 0;
    lds[t] = c; __syncthreads();
    for (int o = 1; o < 256; o <<= 1) {
        int v = (t >= o) ? lds[t - o] : 0;
        __syncthreads(); lds[t] += v; __syncthreads();
    }
    if (i < N) excl[i] = lds[t] - c;
    if (t == 255) partials[blockIdx.x] = lds[255];
}
__global__ __launch_bounds__(512) void k_scan2(
    const int* __restrict__ partials, int* __restrict__ blockoff,
    int* __restrict__ offsets, int nb, int N) {
    __shared__ int lds[512];
    int t = threadIdx.x;
    int c = (t < nb) ? partials[t] : 0;
    lds[t] = c; __syncthreads();
    for (int o = 1; o < 512; o <<= 1) {
        int v = (t >= o) ? lds[t - o] : 0;
        __syncthreads(); lds[t] += v; __syncthreads();
    }
    if (t < nb) blockoff[t] = lds[t] - c;
    if (t == nb - 1) offsets[N] = lds[t];
}
__global__ __launch_bounds__(256) void k_scan3(
    const int* __restrict__ excl, const int* __restrict__ blockoff,
    int* __restrict__ offsets, int* __restrict__ cursor, int N) {
    int i = blockIdx.x * 256 + threadIdx.x;
    if (i < N) {
        int o = excl[i] + blockoff[i >> 8];
        offsets[i] = o; cursor[i] = o;
    }
}

// csrmp[pos] = mp row of kept edge, grouped by dst
__global__ __launch_bounds__(256) void k_scatter(
    const int2* __restrict__ kept, const int* __restrict__ keptCnt,
    const int4* __restrict__ mp4, int* __restrict__ cursor,
    int4* __restrict__ csrmp) {
    int i = blockIdx.x * 256 + threadIdx.x;
    if (i >= *keptCnt) return;
    int2 kd = kept[i];
    int4 rows = mp4[kd.x];
    int pos = atomicAdd(&cursor[kd.y], 1);
    csrmp[pos] = rows;
}

// ---------------------------------------------------------------------------
// Per flagged node (one wave): online softmax + aggregation. Logits computed
// on the fly from P gathers. Writes nftb (bf16) once; fused gate partial dot.
__global__ __launch_bounds__(256) void k_agg(
    const unsigned short* __restrict__ Ybf, const float* __restrict__ P,
    const int4* __restrict__ csrmp, const int* __restrict__ offsets,
    const int* __restrict__ flagged, const int* __restrict__ nf,
    const int* __restrict__ mult, const float* __restrict__ Wth,
    const float* __restrict__ Wg, unsigned short* __restrict__ nftb,
    float* __restrict__ gate_part) {
    int wid = blockIdx.x * 4 + (threadIdx.x >> 6);
    int lane = threadIdx.x & 63;
    if (wid >= *nf) return;
    int n = flagged[wid];
    int m = mult[n];
    int beg = offsets[n], end = offsets[n + 1];
    int h = lane & 7;

    float wth[8];
#pragma unroll
    for (int j = 0; j < 8; ++j) wth[j] = Wth[h * 8 + j];

    float mx[8], den[8], acc[8];
#pragma unroll
    for (int i = 0; i < 8; ++i) { mx[i] = -1e30f; den[i] = 0.f; acc[i] = 0.f; }

    for (int j = beg; j < end; ++j) {
        int4 rows = csrmp[j];
        // s (for head h=lane&7): Yi[r0]+Yi[r3] proj + Yp[r1]+Yp[r2] proj
        float s = P[(size_t)rows.x * 16 + h] + P[(size_t)rows.w * 16 + h]
                + P[(size_t)rows.y * 16 + 8 + h] + P[(size_t)rows.z * 16 + 8 + h];
        float l = 0.f;
#pragma unroll
        for (int jj = 0; jj < 8; ++jj) l += wth[jj] * __shfl(s, jj);
        l = l > 0.f ? l : 0.01f * l;
        // edata[d=lane]
        float ed = bf2f(Ybf[(size_t)rows.x * 128 + lane])
                 + bf2f(Ybf[(size_t)rows.w * 128 + lane])
                 + bf2f(Ybf[(size_t)rows.y * 128 + 64 + lane])
                 + bf2f(Ybf[(size_t)rows.z * 128 + 64 + lane]);
#pragma unroll
        for (int hh = 0; hh < 8; ++hh) {
            float lh = __shfl(l, hh);
            float m2 = fmaxf(mx[hh], lh);
            float sc = __expf(mx[hh] - m2);
            float w = __expf(lh - m2);
            den[hh] = den[hh] * sc + w;
            acc[hh] = acc[hh] * sc + w * ed;
            mx[hh] = m2;
        }
    }
#pragma unroll
    for (int i = 0; i < 8; ++i) {
        float r = (end > beg) ? 1.f / den[i] : 0.f;
        acc[i] *= r;
    }

    unsigned short* base = nftb + (size_t)n * 512;
#pragma unroll
    for (int i = 0; i < 8; ++i) base[i * 64 + lane] = f2bf(acc[i]);

    float wg = Wg[lane];
    float myg = 0.f;
#pragma unroll
    for (int i = 0; i < 8; ++i) {
        float p = acc[i] * wg;
#pragma unroll
        for (int o = 32; o > 0; o >>= 1) p += __shfl_xor(p, o);
        if (lane == i) myg = p;
    }
    if (lane < 8)
        atomicAdd(&gate_part[(blockIdx.x & 1023) * 8 + lane], (float)m * myg);
}

// gate[h] = sum(gate_part)/B + b_gate
__global__ __launch_bounds__(256) void k_gatefinal(
    const float* __restrict__ gate_part, const float* __restrict__ b_gate,
    float* __restrict__ gate, int B) {
    __shared__ float lds[256];
    int t = threadIdx.x;
    int h = t & 7, g = t >> 3;
    float s = 0.f;
    for (int b = g; b < 1024; b += 32) s += gate_part[b * 8 + h];
    lds[t] = s; __syncthreads();
    if (t < 8) {
        float tot = 0.f;
        for (int gg = 0; gg < 32; ++gg) tot += lds[gg * 8 + t];
        gate[t] = tot / (float)B + b_gate[0];
    }
}

// out[b, h*64+d] = nftb[batch_nodes[b]] * gate[h]
__global__ __launch_bounds__(256) void k_output(
    const unsigned short* __restrict__ nftb, const int* __restrict__ batch_nodes,
    const float* __restrict__ gate, float* __restrict__ out, int B) {
    int idx = blockIdx.x * 256 + threadIdx.x;
    int total = B * 128;
    if (idx >= total) return;
    int b = idx >> 7;
    int rem4 = idx & 127;
    int h = rem4 >> 4;
    int n = batch_nodes[b];
    ushort4 v = *(const ushort4*)(nftb + (size_t)n * 512 + rem4 * 4);
    float g = gate[h];
    float4 o;
    o.x = bf2f(v.x) * g; o.y = bf2f(v.y) * g;
    o.z = bf2f(v.z) * g; o.w = bf2f(v.w) * g;
    *(float4*)(out + (size_t)idx * 4) = o;
}

// ---------------------------------------------------------------------------
extern "C" void kernel_launch(void* const* d_in, const int* in_sizes, int n_in,
                              void* d_out, int out_size, void* d_ws, size_t ws_size,
                              hipStream_t stream) {
    const int*   batch_nodes = (const int*)d_in[0];
    const int*   mp          = (const int*)d_in[1];
    const int*   edge_dst    = (const int*)d_in[2];
    const float* feat        = (const float*)d_in[3];
    const float* W_i         = (const float*)d_in[4];
    const float* W_p         = (const float*)d_in[5];
    const float* attn        = (const float*)d_in[6];
    const float* W_th        = (const float*)d_in[7];
    const float* W_gate      = (const float*)d_in[8];
    const float* b_gate      = (const float*)d_in[9];
    float* out = (float*)d_out;

    const int B = in_sizes[0];
    const int E = in_sizes[2];
    const int N = in_sizes[3] / 128;
    const int nb_scan = (N + 255) / 256;

    char* w = (char*)d_ws;
    auto alloc = [&](size_t bytes) -> void* {
        void* p = (void*)w;
        w += (bytes + 255) & ~(size_t)255;
        return p;
    };
    // contiguous zero region: mult[N], count[N], gate_part[8192], nf, keptCnt
    size_t zbytes = (size_t)N * 4 + (size_t)N * 4 + 8192 * 4 + 256;
    char* zb            = (char*)alloc(zbytes);
    int*   mult         = (int*)zb;
    int*   count        = (int*)(zb + (size_t)N * 4);
    float* gate_part    = (float*)(zb + 2 * (size_t)N * 4);
    int*   nf           = (int*)(zb + 2 * (size_t)N * 4 + 8192 * 4);
    int*   keptCnt      = nf + 1;

    unsigned short* Whi = (unsigned short*)alloc(16384 * 2);
    unsigned short* Wlo = (unsigned short*)alloc(16384 * 2);
    unsigned short* Ybf = (unsigned short*)alloc((size_t)N * 128 * 2);   // 25.6 MB
    float* P            = (float*)alloc((size_t)N * 16 * 4);             // 6.4 MB
    int*   flagged      = (int*)alloc((size_t)N * 4);
    int2*  kept         = (int2*)alloc((size_t)E * 8);                   // 2.4 MB
    int*   excl         = (int*)alloc((size_t)N * 4);
    int*   offsets      = (int*)alloc((size_t)(N + 1) * 4);
    int*   cursor       = (int*)alloc((size_t)N * 4);
    int*   partials     = (int*)alloc(512 * 4);
    int*   blockoff     = (int*)alloc(512 * 4);
    int4*  csrmp        = (int4*)alloc((size_t)E * 16);                  // 4.8 MB
    unsigned short* nftb = (unsigned short*)alloc((size_t)N * 512 * 2);  // 102.4 MB
    float* gate         = (float*)alloc(256);

    hipMemsetAsync(zb, 0, zbytes, stream);

    k_prep<<<64 + (B + 255) / 256, 256, 0, stream>>>(
        W_i, W_p, Whi, Wlo, batch_nodes, mult, flagged, nf, B);
    k_dense<<<(N + 63) / 64, 256, 0, stream>>>(feat, Whi, Wlo, attn, Ybf, P, N);
    k_hist<<<(E + 255) / 256, 256, 0, stream>>>(edge_dst, mult, count, kept, keptCnt, E);
    k_scan1<<<nb_scan, 256, 0, stream>>>(count, excl, partials, N);
    k_scan2<<<1, 512, 0, stream>>>(partials, blockoff, offsets, nb_scan, N);
    k_scan3<<<nb_scan, 256, 0, stream>>>(excl, blockoff, offsets, cursor, N);
    k_scatter<<<(E + 255) / 256, 256, 0, stream>>>(kept, keptCnt, (const int4*)mp, cursor, csrmp);
    k_agg<<<(B + 3) / 4, 256, 0, stream>>>(Ybf, P, csrmp, offsets, flagged, nf,
                                           mult, W_th, W_gate, nftb, gate_part);
    k_gatefinal<<<1, 256, 0, stream>>>(gate_part, b_gate, gate, B);
    k_output<<<(B * 128 + 255) / 256, 256, 0, stream>>>(nftb, batch_nodes, gate, out, B);
}